// Round 9
// baseline (63.123 us; speedup 1.0000x reference)
//
#include <hip/hip_runtime.h>

// Batched 10-qubit statevector sim, one wave64 per batch element.
// State: 1024 complex amps = 16 complex per lane (j = lane<<4 | r).
// CNOT rings folded away over GF(2): layer-2 RX on wire w becomes
//   psi'[j] = c*psi[j] - i*s*psi[j ^ d_w],  d_w = A^-1 e_w
// Measurement: z_i = WHT of |psi|^2 at mask g_i = row i of A^2.
// Cross-lane: DPP quad_perm (xor1/2/3, verified r4), row_ror:8 (xor8,
// verified r8), row_mirror/row_half_mirror (xor15/xor7, NEW this round —
// mirrors are direction-free xor masks; composition P_a∘P_b = P_{a^b}
// gives any xor in bits 0-3 as <=2 DPP). ds_swizzle/shfl only for masks
// touching lane bits 4,5 (104 DS ops/wave, was 172).
// permlane16/32_swap sum-trick CONDEMNED (round-5 absmax=2.96).

template<int CTRL>
__device__ __forceinline__ float dppf(float v) {
  int i = __builtin_bit_cast(int, v);
  i = __builtin_amdgcn_update_dpp(i, i, CTRL, 0xF, 0xF, false);
  return __builtin_bit_cast(float, i);
}
template<int PAT>
__device__ __forceinline__ float swzf(float v) {
  int i = __builtin_bit_cast(int, v);
  i = __builtin_amdgcn_ds_swizzle(i, PAT);
  return __builtin_bit_cast(float, i);
}

// partner fetch psi[. ^ (DLN<<4 | DL)]
template<int DL, int DLN>
__device__ __forceinline__ float fetchp(const float (&a)[16], int r) {
  float v = a[r ^ DL];
  if constexpr (DLN == 0)       return v;
  else if constexpr (DLN == 1)  return dppf<0xB1>(v);            // quad xor1
  else if constexpr (DLN == 3)  return dppf<0x1B>(v);            // quad xor3
  else if constexpr (DLN == 6)  return dppf<0xB1>(dppf<0x141>(v)); // 7^1: half_mirror+quad1
  else if constexpr (DLN == 12) return dppf<0x1B>(dppf<0x140>(v)); // 15^3: mirror+quad3
  else if constexpr (DLN == 24) return swzf<0x601F>(v);          // swizzle xor24
  else                          return __shfl_xor(v, DLN);       // 32, 48 (bit5)
}

template<int DL, int DLN>
__device__ __forceinline__ void apply_gate(float (&ar)[16], float (&ai)[16],
                                           float c, float s) {
  float nr[16], ni[16];
#pragma unroll
  for (int r = 0; r < 16; ++r) {
    float pr = fetchp<DL, DLN>(ar, r);
    float pi = fetchp<DL, DLN>(ai, r);
    // new = c*mine - i*s*partner  => re: c*ar + s*pi ; im: c*ai - s*pr
    nr[r] = fmaf(s, pi, c * ar[r]);
    ni[r] = fmaf(-s, pr, c * ai[r]);
  }
#pragma unroll
  for (int r = 0; r < 16; ++r) { ar[r] = nr[r]; ai[r] = ni[r]; }
}

// signed 64-lane WHT of one register: lane L ends with sum_L' (-1)^<L,L'> v_L'
__device__ __forceinline__ float lane_wht(float v, float g1, float g2, float g4,
                                          float g8, float g16, float g32) {
  v = fmaf(g1,  v, dppf<0xB1>(v));               // xor1  quad (verified)
  v = fmaf(g2,  v, dppf<0x4E>(v));               // xor2  quad (verified)
  v = fmaf(g4,  v, dppf<0x1B>(dppf<0x141>(v)));  // xor4 = 7^3 mirror+quad (NEW)
  v = fmaf(g8,  v, dppf<0x128>(v));              // xor8  row_ror:8 (verified r8)
  v = fmaf(g16, v, swzf<0x401F>(v));             // xor16 swizzle (verified)
  v = fmaf(g32, v, __shfl_xor(v, 32));           // xor32 shfl (verified)
  return v;
}

__global__ void __launch_bounds__(256)
qsim_kernel(const float* __restrict__ x, const float* __restrict__ wts,
            float* __restrict__ out, int B) {
  const int lane = threadIdx.x & 63;
  const int b = blockIdx.x * 4 + (threadIdx.x >> 6);
  if (b >= B) return;
  const float* xb = x + b * 10;

  // ---- lane prefix: product over wires 4..9 selected by lane bits (on the fly)
  float Pr = 1.0f, Pi = 0.0f;
#pragma unroll
  for (int w = 4; w < 10; ++w) {
    float xh = 0.5f * xb[w];
    float t1 = 0.5f * wts[w];
    float cx = __cosf(xh), sx = __sinf(xh);
    float c1 = __cosf(t1), s1w = __sinf(t1);
    int bit = (lane >> (w - 4)) & 1;
    float qr = c1 * (bit ? sx : cx);
    float qi = -s1w * (bit ? cx : sx);
    float nr = Pr * qr - Pi * qi;
    float ni = Pr * qi + Pi * qr;
    Pr = nr; Pi = ni;
  }

  // ---- wires 0..3: q_w = RX(th1) RY(x)|0>, tensor doubling into registers
  float ar[16], ai[16];
  ar[0] = Pr; ai[0] = Pi;
#pragma unroll
  for (int w = 0; w < 4; ++w) {
    float xh = 0.5f * xb[w];
    float t1 = 0.5f * wts[w];
    float cx = __cosf(xh), sx = __sinf(xh);
    float c1 = __cosf(t1), s1w = __sinf(t1);
    float q0r = c1 * cx, q0i = -s1w * sx;
    float q1r = c1 * sx, q1i = -s1w * cx;
#pragma unroll
    for (int r = 0; r < 8; ++r) {
      if (r < (1 << w)) {
        float lr = ar[r], li = ai[r];
        ar[r + (1 << w)] = lr * q1r - li * q1i;
        ai[r + (1 << w)] = lr * q1i + li * q1r;
        ar[r] = lr * q0r - li * q0i;
        ai[r] = lr * q0i + li * q0r;
      }
    }
  }

  // ---- layer-2 cos/sin
  float c2[10], s2v[10];
#pragma unroll
  for (int w = 0; w < 10; ++w) {
    float t2 = 0.5f * wts[10 + w];
    c2[w] = __cosf(t2);
    s2v[w] = __sinf(t2);
  }

  // ---- layer-2 RX gates, XOR masks d_w (template <d&15, d>>4>)
  apply_gate<3, 0>(ar, ai, c2[0], s2v[0]);    // {0,1}   reg-only
  apply_gate<6, 0>(ar, ai, c2[1], s2v[1]);    // {1,2}   reg-only
  apply_gate<12, 0>(ar, ai, c2[2], s2v[2]);   // {2,3}   reg-only
  apply_gate<8, 1>(ar, ai, c2[3], s2v[3]);    // {3,4}   DPP quad
  apply_gate<0, 3>(ar, ai, c2[4], s2v[4]);    // {4,5}   DPP quad
  apply_gate<0, 6>(ar, ai, c2[5], s2v[5]);    // {5,6}   DPP mirror+quad (NEW)
  apply_gate<0, 12>(ar, ai, c2[6], s2v[6]);   // {6,7}   DPP mirror+quad (NEW)
  apply_gate<0, 24>(ar, ai, c2[7], s2v[7]);   // {7,8}   swizzle
  apply_gate<0, 48>(ar, ai, c2[8], s2v[8]);   // {8,9}   shfl
  apply_gate<3, 32>(ar, ai, c2[9], s2v[9]);   // {0,1,9} shfl

  // ---- probabilities + exact in-lane WHT over the 4 register bits
  float p[16];
#pragma unroll
  for (int r = 0; r < 16; ++r) p[r] = ar[r] * ar[r] + ai[r] * ai[r];
#pragma unroll
  for (int stp = 0; stp < 4; ++stp) {
    const int st = 1 << stp;
#pragma unroll
    for (int r = 0; r < 16; ++r) {
      if (!(r & st)) {
        float a0 = p[r], a1 = p[r | st];
        p[r] = a0 + a1;
        p[r | st] = a0 - a1;
      }
    }
  }

  // ---- 64-lane WHT on the 4 needed registers; lane L = coeff at lane-mask L
  const float g1  = (lane & 1)  ? -1.0f : 1.0f;
  const float g2  = (lane & 2)  ? -1.0f : 1.0f;
  const float g4  = (lane & 4)  ? -1.0f : 1.0f;
  const float g8  = (lane & 8)  ? -1.0f : 1.0f;
  const float g16 = (lane & 16) ? -1.0f : 1.0f;
  const float g32 = (lane & 32) ? -1.0f : 1.0f;
  float w5  = lane_wht(p[5],  g1, g2, g4, g8, g16, g32);
  float w10 = lane_wht(p[10], g1, g2, g4, g8, g16, g32);
  float w11 = lane_wht(p[11], g1, g2, g4, g8, g16, g32);
  float w13 = lane_wht(p[13], g1, g2, g4, g8, g16, g32);

  // ---- z_i lives in lane (g_i>>4), register map below; g_i = row i of A^2
  // i : (reg, lane) = 0:(11,42) 1:(13,63) 2:(10,63) 3:(5,63) 4:(10,62)
  //                   5:(5,61) 6:(10,58) 7:(5,53) 8:(10,42) 9:(5,21)
  float* ob = out + b * 10;
  if (lane == 42) { ob[0] = w11; ob[8] = w10; }
  if (lane == 63) { ob[1] = w13; ob[2] = w10; ob[3] = w5; }
  if (lane == 62) { ob[4] = w10; }
  if (lane == 61) { ob[5] = w5; }
  if (lane == 58) { ob[6] = w10; }
  if (lane == 53) { ob[7] = w5; }
  if (lane == 21) { ob[9] = w5; }
}

extern "C" void kernel_launch(void* const* d_in, const int* in_sizes, int n_in,
                              void* d_out, int out_size, void* d_ws, size_t ws_size,
                              hipStream_t stream) {
  const float* x = (const float*)d_in[0];
  const float* wts = (const float*)d_in[1];
  float* out = (float*)d_out;
  const int B = in_sizes[0] / 10;
  const int blocks = (B + 3) / 4;  // 4 waves (=4 batch elems) per 256-thread block
  qsim_kernel<<<blocks, 256, 0, stream>>>(x, wts, out, B);
}